// Round 1
// baseline (300.955 us; speedup 1.0000x reference)
//
#include <hip/hip_runtime.h>

// LSTM (H=8, I=1), B=4096, T=2048, then FC [8->4].
//
// Mapping: 16 lanes per batch element (wave64 = 4 batches).
//   lane lg in [0,16): computes gate rows gA=lg (i/f block) and gB=lg+16 (g/o
//   block) of the 4H=32 gate vector; owns c_j, h_j for j = lg&7 (h duplicated
//   in both halves of the 16-lane row -> DPP row_ror:1 acts as mod-8 rotate).
// All per-step cross-lane traffic is DPP (VALU latency). The only DS ops are
// 16 ds_swizzle broadcasts of x per 16-step block, hoisted off the serial
// recurrence chain. No LDS / no global loads inside the step chain.

#define LOG2E 1.4426950408889634f

template <int CTRL>
__device__ __forceinline__ float dpp_mov(float v) {
  return __int_as_float(
      __builtin_amdgcn_update_dpp(0, __float_as_int(v), CTRL, 0xF, 0xF, true));
}

#define ROR1 0x121  // dst lane i <- src lane (i-1) & 15
#define ROR4 0x124  // dst lane i <- src lane (i-4) & 15
#define ROR8 0x128  // dst lane i <- src lane (i-8) & 15

__device__ __forceinline__ float fast_ex2(float x) {
#if __has_builtin(__builtin_amdgcn_exp2f)
  return __builtin_amdgcn_exp2f(x);
#else
  return __exp2f(x);
#endif
}

__device__ __forceinline__ float fast_rcp(float x) {
#if __has_builtin(__builtin_amdgcn_rcpf)
  return __builtin_amdgcn_rcpf(x);
#else
  return 1.0f / x;
#endif
}

// Broadcast lane s (0..15) of each 16-lane subgroup to the whole subgroup.
// ds_swizzle BitMode: src = ((self & AND) | OR) ^ XOR; AND=0x10 keeps the
// subgroup bit within the 32-lane half, OR=s selects the source lane.
#define XBCAST(s) \
  __int_as_float(__builtin_amdgcn_ds_swizzle(__float_as_int(xv), ((s) << 5) | 0x10))

__global__ __launch_bounds__(256) void lstm_kernel(
    const float* __restrict__ x, const float* __restrict__ w_ih,
    const float* __restrict__ w_hh, const float* __restrict__ b_ih,
    const float* __restrict__ b_hh, const float* __restrict__ w_fc,
    const float* __restrict__ b_fc, float* __restrict__ out, int B, int T) {
  const int tid = threadIdx.x;
  const int lg = tid & 15;         // lane within 16-lane group
  const int grp = tid >> 4;        // group within block (0..15)
  const int b = blockIdx.x * 16 + grp;  // batch element

  const int gA = lg;        // gate row in [0,16): i (lg<8) or f (lg>=8)
  const int gB = lg + 16;   // gate row in [16,32): g (lg<8) or o (lg>=8)
  const int j = lg & 7;     // owned h/c element
  const bool lo8 = (lg < 8);

  // Per-lane weights for the rotation schedule: round r sees h_{(lg-r)&7}.
  float wA[8], wB[8];
#pragma unroll
  for (int r = 0; r < 8; ++r) {
    const int jr = (lg - r) & 7;
    wA[r] = w_hh[gA * 8 + jr];
    wB[r] = w_hh[gB * 8 + jr];
  }
  const float wihA = w_ih[gA], wihB = w_ih[gB];
  const float biasA = b_ih[gA] + b_hh[gA];
  const float biasB = b_ih[gB] + b_hh[gB];
  // Unified activation: act = AB * rcp(1 + exp2(mB * g)) + BB
  //   sigmoid: m=-log2e, A=1, B=0;  tanh: m=-2log2e, A=2, B=-1.
  const float mB = lo8 ? (-2.0f * LOG2E) : (-LOG2E);  // gB is tanh iff lg<8
  const float AB = lo8 ? 2.0f : 1.0f;
  const float BB = lo8 ? -1.0f : 0.0f;

  float hh = 0.0f;  // h_{lg&7}, duplicated across both halves of the 16-row
  float cc = 0.0f;  // c_{lg&7}

  const float* xp = x + (size_t)b * T + lg;
  float xv = *xp;  // x[b, blk*16 + lg]
  const int NBLK = T / 16;

  for (int blk = 0; blk < NBLK; ++blk) {
    // Prefetch next 16 timesteps (wave-uniform predicate, no divergence).
    xp += (blk < NBLK - 1) ? 16 : 0;
    const float xvn = *xp;

    // Off-chain: broadcast the 16 x values of this block to all lanes.
    float xb[16];
    xb[0] = XBCAST(0);   xb[1] = XBCAST(1);   xb[2] = XBCAST(2);
    xb[3] = XBCAST(3);   xb[4] = XBCAST(4);   xb[5] = XBCAST(5);
    xb[6] = XBCAST(6);   xb[7] = XBCAST(7);   xb[8] = XBCAST(8);
    xb[9] = XBCAST(9);   xb[10] = XBCAST(10); xb[11] = XBCAST(11);
    xb[12] = XBCAST(12); xb[13] = XBCAST(13); xb[14] = XBCAST(14);
    xb[15] = XBCAST(15);

#pragma unroll
    for (int s = 0; s < 16; ++s) {
      // ---- gates: g = x*w_ih + bias + sum_j h_j * w_hh[g][j] (systolic DPP)
      float g0 = fmaf(xb[s], wihA, biasA);
      float g1 = fmaf(xb[s], wihB, biasB);
      const float r0 = hh;
      const float r4 = dpp_mov<ROR4>(hh);
      float g0b = r4 * wA[4];
      float g1b = r4 * wB[4];
      g0 = fmaf(r0, wA[0], g0);
      g1 = fmaf(r0, wB[0], g1);
      const float r1 = dpp_mov<ROR1>(r0);
      const float r5 = dpp_mov<ROR1>(r4);
      g0 = fmaf(r1, wA[1], g0);
      g1 = fmaf(r1, wB[1], g1);
      g0b = fmaf(r5, wA[5], g0b);
      g1b = fmaf(r5, wB[5], g1b);
      const float r2 = dpp_mov<ROR1>(r1);
      const float r6 = dpp_mov<ROR1>(r5);
      g0 = fmaf(r2, wA[2], g0);
      g1 = fmaf(r2, wB[2], g1);
      g0b = fmaf(r6, wA[6], g0b);
      g1b = fmaf(r6, wB[6], g1b);
      const float r3 = dpp_mov<ROR1>(r2);
      const float r7 = dpp_mov<ROR1>(r6);
      g0 = fmaf(r3, wA[3], g0);
      g1 = fmaf(r3, wB[3], g1);
      g0b = fmaf(r7, wA[7], g0b);
      g1b = fmaf(r7, wB[7], g1b);
      g0 += g0b;
      g1 += g1b;

      // ---- activations
      const float eA = fast_ex2(g0 * (-LOG2E));
      const float sA = fast_rcp(1.0f + eA);               // sigmoid(i or f)
      const float eB = fast_ex2(g1 * mB);
      const float sB = fmaf(fast_rcp(1.0f + eB), AB, BB);  // tanh(g) / sig(o)

      // ---- exchange between the two 8-halves: get partner's (act0, act1)
      const float xA = dpp_mov<ROR8>(sA);
      const float xB = dpp_mov<ROR8>(sB);
      const float iv = lo8 ? sA : xA;
      const float fv = lo8 ? xA : sA;
      const float gv = lo8 ? sB : xB;
      const float ov = lo8 ? xB : sB;

      // ---- state update (redundant on both halves -> keeps h duplicated)
      cc = fmaf(fv, cc, iv * gv);
      const float eC = fast_ex2(cc * (-2.0f * LOG2E));
      const float th = fmaf(fast_rcp(1.0f + eC), 2.0f, -1.0f);
      hh = ov * th;
    }
    xv = xvn;
  }

  // ---- final FC: out[b, q] = b_fc[q] + sum_j h_j * w_fc[q, j], q in [0,4)
  __shared__ float sh[16 * 8];
  if (lo8) sh[grp * 8 + j] = hh;
  __syncthreads();
  if (lg < 4) {
    float acc = b_fc[lg];
#pragma unroll
    for (int k = 0; k < 8; ++k) acc = fmaf(sh[grp * 8 + k], w_fc[lg * 8 + k], acc);
    out[(size_t)b * 4 + lg] = acc;
  }
}

extern "C" void kernel_launch(void* const* d_in, const int* in_sizes, int n_in,
                              void* d_out, int out_size, void* d_ws,
                              size_t ws_size, hipStream_t stream) {
  const float* x = (const float*)d_in[0];
  const float* w_ih = (const float*)d_in[1];
  const float* w_hh = (const float*)d_in[2];
  const float* b_ih = (const float*)d_in[3];
  const float* b_hh = (const float*)d_in[4];
  const float* w_fc = (const float*)d_in[5];
  const float* b_fc = (const float*)d_in[6];
  float* out = (float*)d_out;

  const int T = 2048;
  const int B = in_sizes[0] / T;  // 4096

  dim3 grid(B / 16);   // 16 batches per 256-thread block
  dim3 block(256);
  hipLaunchKernelGGL(lstm_kernel, grid, block, 0, stream, x, w_ih, w_hh, b_ih,
                     b_hh, w_fc, b_fc, out, B, T);
}

// Round 2
// 291.919 us; speedup vs baseline: 1.0310x; 1.0310x over previous
//
#include <hip/hip_runtime.h>

// LSTM (H=8, I=1), B=4096, T=2048, then FC [8->4].
//
// Mapping: 16 lanes per batch element (wave64 = 4 batches, 1024 waves total
// = exactly 1 wave/SIMD on 256 CUs -> occupancy is grid-limited by design).
//   lane lg in [0,16): computes gate rows gA=lg (i/f block) and gB=lg+16 (g/o
//   block); owns c_j, h_j for j = lg&7 (h duplicated in both 8-halves of the
//   16-lane row -> DPP row_ror:r acts as mod-8 rotate for r in 1..7).
// R2 changes vs R1:
//   - independent DPP rotations (row_ror:1..7 straight from hh), no serial
//     DPP chain.
//   - v_pk_fma_f32 packing: the two gate rows per lane accumulate as float2;
//     splat operands fold to op_sel on gfx950 (packed-fp32 VOP3P).
//   - x*w_ih+bias pairs precomputed per 16-step block (off the serial chain).
//   - hh = fma(2*ov, rcp, -ov) folds the tanh affine + output mul.

typedef float v2f __attribute__((ext_vector_type(2)));

#define LOG2E 1.4426950408889634f

template <int CTRL>
__device__ __forceinline__ float dpp_mov(float v) {
  return __int_as_float(
      __builtin_amdgcn_update_dpp(0, __float_as_int(v), CTRL, 0xF, 0xF, true));
}
#define ROR(n) (0x120 + (n))  // row_ror:n  (dst lane i <- src lane (i-n)&15)

__device__ __forceinline__ float fast_ex2(float x) {
#if __has_builtin(__builtin_amdgcn_exp2f)
  return __builtin_amdgcn_exp2f(x);
#else
  return __exp2f(x);
#endif
}

__device__ __forceinline__ float fast_rcp(float x) {
#if __has_builtin(__builtin_amdgcn_rcpf)
  return __builtin_amdgcn_rcpf(x);
#else
  return 1.0f / x;
#endif
}

__device__ __forceinline__ v2f fma2(v2f a, v2f b, v2f c) {
  return __builtin_elementwise_fma(a, b, c);
}
__device__ __forceinline__ v2f splat2(float v) { return (v2f){v, v}; }

// Broadcast lane s (0..15) of each 16-lane subgroup to the whole subgroup.
// ds_swizzle BitMode: src = ((self & AND) | OR); AND=0x10 keeps the subgroup
// bit within the 32-lane half, OR=s selects the source lane.
#define XBCAST(s) \
  __int_as_float(__builtin_amdgcn_ds_swizzle(__float_as_int(xv), ((s) << 5) | 0x10))

__global__ __launch_bounds__(256) void lstm_kernel(
    const float* __restrict__ x, const float* __restrict__ w_ih,
    const float* __restrict__ w_hh, const float* __restrict__ b_ih,
    const float* __restrict__ b_hh, const float* __restrict__ w_fc,
    const float* __restrict__ b_fc, float* __restrict__ out, int B, int T) {
  const int tid = threadIdx.x;
  const int lg = tid & 15;              // lane within 16-lane group
  const int grp = tid >> 4;             // group within block (0..15)
  const int b = blockIdx.x * 16 + grp;  // batch element

  const int gA = lg;       // gate row in [0,16): i (lg<8) or f (lg>=8)
  const int gB = lg + 16;  // gate row in [16,32): g (lg<8) or o (lg>=8)
  const int j = lg & 7;    // owned h/c element
  const bool lo8 = (lg < 8);

  // Per-lane packed weights for the rotation schedule: round r sees h_{(lg-r)&7}.
  v2f w2[8];
#pragma unroll
  for (int r = 0; r < 8; ++r) {
    const int jr = (lg - r) & 7;
    w2[r] = (v2f){w_hh[gA * 8 + jr], w_hh[gB * 8 + jr]};
  }
  const v2f wih2 = (v2f){w_ih[gA], w_ih[gB]};
  const v2f bias2 = (v2f){b_ih[gA] + b_hh[gA], b_ih[gB] + b_hh[gB]};
  // Unified activation: act = A * rcp(1 + exp2(m * g)) + Bc
  //   sigmoid: m=-log2e, A=1, Bc=0;  tanh: m=-2log2e, A=2, Bc=-1.
  const float mB = lo8 ? (-2.0f * LOG2E) : (-LOG2E);  // gB is tanh iff lg<8
  const float AB = lo8 ? 2.0f : 1.0f;
  const float BB = lo8 ? -1.0f : 0.0f;
  const v2f mm2 = (v2f){-LOG2E, mB};

  float hh = 0.0f;  // h_{lg&7}, duplicated across both halves of the 16-row
  float cc = 0.0f;  // c_{lg&7}

  const float* xp = x + (size_t)b * T + lg;
  float xv = *xp;  // x[b, blk*16 + lg]
  const int NBLK = T / 16;

  for (int blk = 0; blk < NBLK; ++blk) {
    // Prefetch next 16 timesteps (wave-uniform predicate, no divergence).
    xp += (blk < NBLK - 1) ? 16 : 0;
    const float xvn = *xp;

    // Off-chain: broadcast this block's 16 x values and fold in w_ih + bias.
    v2f xg[16];
#pragma unroll
    for (int s = 0; s < 16; ++s) {
      // ds_swizzle pattern must be a compile-time constant -> switch via macro
      float xb;
      switch (s) {
        case 0: xb = XBCAST(0); break;   case 1: xb = XBCAST(1); break;
        case 2: xb = XBCAST(2); break;   case 3: xb = XBCAST(3); break;
        case 4: xb = XBCAST(4); break;   case 5: xb = XBCAST(5); break;
        case 6: xb = XBCAST(6); break;   case 7: xb = XBCAST(7); break;
        case 8: xb = XBCAST(8); break;   case 9: xb = XBCAST(9); break;
        case 10: xb = XBCAST(10); break; case 11: xb = XBCAST(11); break;
        case 12: xb = XBCAST(12); break; case 13: xb = XBCAST(13); break;
        case 14: xb = XBCAST(14); break; default: xb = XBCAST(15); break;
      }
      xg[s] = fma2(splat2(xb), wih2, bias2);
    }

#pragma unroll
    for (int s = 0; s < 16; ++s) {
      // ---- matvec: gates = xg[s] + sum_r h_{(lg-r)&7} * w2[r]
      // All 7 rotations issue independently from hh (no DPP chain).
      const float r1 = dpp_mov<ROR(1)>(hh);
      const float r2 = dpp_mov<ROR(2)>(hh);
      const float r3 = dpp_mov<ROR(3)>(hh);
      const float r4 = dpp_mov<ROR(4)>(hh);
      const float r5 = dpp_mov<ROR(5)>(hh);
      const float r6 = dpp_mov<ROR(6)>(hh);
      const float r7 = dpp_mov<ROR(7)>(hh);
      v2f acc0 = fma2(splat2(hh), w2[0], xg[s]);
      v2f acc1 = splat2(r1) * w2[1];
      acc0 = fma2(splat2(r2), w2[2], acc0);
      acc1 = fma2(splat2(r3), w2[3], acc1);
      acc0 = fma2(splat2(r4), w2[4], acc0);
      acc1 = fma2(splat2(r5), w2[5], acc1);
      acc0 = fma2(splat2(r6), w2[6], acc0);
      acc1 = fma2(splat2(r7), w2[7], acc1);
      const v2f gg = acc0 + acc1;

      // ---- activations (packed exp args, scalar trans ops)
      const v2f ea = gg * mm2;
      const float e0 = fast_ex2(ea.x);
      const float e1 = fast_ex2(ea.y);
      const float sA = fast_rcp(1.0f + e0);                // sigmoid(i or f)
      const float sB = fmaf(fast_rcp(1.0f + e1), AB, BB);  // tanh(g)/sig(o)

      // ---- exchange between the two 8-halves
      const float xA = dpp_mov<ROR(8)>(sA);
      const float xB = dpp_mov<ROR(8)>(sB);
      const float iv = lo8 ? sA : xA;
      const float fv = lo8 ? xA : sA;
      const float gv = lo8 ? sB : xB;
      const float ov = lo8 ? xB : sB;

      // ---- state update (redundant on both halves -> keeps h duplicated)
      cc = fmaf(fv, cc, iv * gv);
      const float ec = fast_ex2(cc * (-2.0f * LOG2E));
      const float rc = fast_rcp(1.0f + ec);
      const float ov2 = ov + ov;       // off-chain (parallel with exp)
      hh = fmaf(ov2, rc, -ov);         // ov*tanh(cc), neg is a free modifier
    }
    xv = xvn;
  }

  // ---- final FC: out[b, q] = b_fc[q] + sum_k h_k * w_fc[q, k], q in [0,4)
  __shared__ float sh[16 * 8];
  if (lo8) sh[grp * 8 + j] = hh;
  __syncthreads();
  if (lg < 4) {
    float acc = b_fc[lg];
#pragma unroll
    for (int k = 0; k < 8; ++k)
      acc = fmaf(sh[grp * 8 + k], w_fc[lg * 8 + k], acc);
    out[(size_t)b * 4 + lg] = acc;
  }
}

extern "C" void kernel_launch(void* const* d_in, const int* in_sizes, int n_in,
                              void* d_out, int out_size, void* d_ws,
                              size_t ws_size, hipStream_t stream) {
  const float* x = (const float*)d_in[0];
  const float* w_ih = (const float*)d_in[1];
  const float* w_hh = (const float*)d_in[2];
  const float* b_ih = (const float*)d_in[3];
  const float* b_hh = (const float*)d_in[4];
  const float* w_fc = (const float*)d_in[5];
  const float* b_fc = (const float*)d_in[6];
  float* out = (float*)d_out;

  const int T = 2048;
  const int B = in_sizes[0] / T;  // 4096

  dim3 grid(B / 16);  // 16 batches per 256-thread block
  dim3 block(256);
  hipLaunchKernelGGL(lstm_kernel, grid, block, 0, stream, x, w_ih, w_hh, b_ih,
                     b_hh, w_fc, b_fc, out, B, T);
}

// Round 3
// 276.974 us; speedup vs baseline: 1.0866x; 1.0540x over previous
//
#include <hip/hip_runtime.h>

// LSTM (H=8, I=1), B=4096, T=2048, then FC [8->4].
//
// Mapping: 16 lanes per batch element (wave64 = 4 batches; 1024 waves total =
// 1 wave/SIMD on 256 CUs). Lane lg in [0,16): gate rows gA=lg (i|f), gB=lg+16
// (g|o); owns c_j,h_j for j=lg&7, h duplicated in both 8-halves so DPP
// row_ror:r acts as rotate mod 8.
//
// R3 (chain-latency focused; R2 showed we are RAW-latency-bound, not
// issue-bound):
//  - exp2 gate scale folded into w_hh/w_ih/bias (k-scaled c state): -2 hops
//  - 4-accumulator matvec tree: -1 hop
//  - iv*gv computed pre-rotate (ROR8 of the product): -1 hop on the c-chain
//  - next-block xg (ds_swizzle+fma) pipelined into the step loop: stall filler

typedef float v2f __attribute__((ext_vector_type(2)));

#define LOG2E 1.4426950408889634f

template <int CTRL>
__device__ __forceinline__ float dpp_mov(float v) {
  return __int_as_float(
      __builtin_amdgcn_update_dpp(0, __float_as_int(v), CTRL, 0xF, 0xF, true));
}
#define ROR(n) (0x120 + (n))  // row_ror:n within 16-lane rows

__device__ __forceinline__ float fast_ex2(float x) {
#if __has_builtin(__builtin_amdgcn_exp2f)
  return __builtin_amdgcn_exp2f(x);
#else
  return __exp2f(x);
#endif
}
__device__ __forceinline__ float fast_rcp(float x) {
#if __has_builtin(__builtin_amdgcn_rcpf)
  return __builtin_amdgcn_rcpf(x);
#else
  return 1.0f / x;
#endif
}
__device__ __forceinline__ v2f fma2(v2f a, v2f b, v2f c) {
  return __builtin_elementwise_fma(a, b, c);
}
__device__ __forceinline__ v2f splat2(float v) { return (v2f){v, v}; }

// Broadcast lane s (0..15) of each 16-lane subgroup: BitMode and=0x10|or=s.
#define XBCAST(v, s) \
  __int_as_float(__builtin_amdgcn_ds_swizzle(__float_as_int(v), ((s) << 5) | 0x10))

__device__ __forceinline__ float xbcast_s(float v, int s) {
  switch (s) {
    case 0: return XBCAST(v, 0);   case 1: return XBCAST(v, 1);
    case 2: return XBCAST(v, 2);   case 3: return XBCAST(v, 3);
    case 4: return XBCAST(v, 4);   case 5: return XBCAST(v, 5);
    case 6: return XBCAST(v, 6);   case 7: return XBCAST(v, 7);
    case 8: return XBCAST(v, 8);   case 9: return XBCAST(v, 9);
    case 10: return XBCAST(v, 10); case 11: return XBCAST(v, 11);
    case 12: return XBCAST(v, 12); case 13: return XBCAST(v, 13);
    case 14: return XBCAST(v, 14); default: return XBCAST(v, 15);
  }
}

// One 16-step block: consume XGC[s], build XGN[s] from XNEXT (next block's x).
#define PROCESS_BLOCK(XGC, XGN, XNEXT)                                     \
  _Pragma("unroll") for (int s = 0; s < 16; ++s) {                         \
    XGN[s] = fma2(splat2(xbcast_s((XNEXT), s)), wih2, bias2);              \
    const v2f xgs = XGC[s];                                                \
    const float r1 = dpp_mov<ROR(1)>(hh);                                  \
    const float r2 = dpp_mov<ROR(2)>(hh);                                  \
    const float r3 = dpp_mov<ROR(3)>(hh);                                  \
    const float r4 = dpp_mov<ROR(4)>(hh);                                  \
    const float r5 = dpp_mov<ROR(5)>(hh);                                  \
    const float r6 = dpp_mov<ROR(6)>(hh);                                  \
    const float r7 = dpp_mov<ROR(7)>(hh);                                  \
    v2f t0 = fma2(splat2(hh), wsc[0], xgs);                                \
    v2f t1 = splat2(r1) * wsc[1];                                          \
    v2f t2 = splat2(r4) * wsc[4];                                          \
    v2f t3 = splat2(r5) * wsc[5];                                          \
    t0 = fma2(splat2(r2), wsc[2], t0);                                     \
    t1 = fma2(splat2(r3), wsc[3], t1);                                     \
    t2 = fma2(splat2(r6), wsc[6], t2);                                     \
    t3 = fma2(splat2(r7), wsc[7], t3);                                     \
    const v2f gg = (t0 + t1) + (t2 + t3);                                  \
    const float e0 = fast_ex2(gg.x); /* gate scale pre-folded in weights */ \
    const float e1 = fast_ex2(gg.y);                                       \
    const float sA = fast_rcp(1.0f + e0);          /* sigmoid(i|f) */      \
    const float sB = fmaf(fast_rcp(1.0f + e1), AB, BB); /* k*tanh(g)|sig(o) */ \
    const float p1 = sA * sB;                                              \
    const float xA = dpp_mov<ROR(8)>(sA);                                  \
    const float xB = dpp_mov<ROR(8)>(sB);                                  \
    const float xp1 = dpp_mov<ROR(8)>(p1);                                 \
    const float fv = lo8 ? xA : sA;                                        \
    const float ov = lo8 ? xB : sB;                                        \
    const float pp = lo8 ? p1 : xp1; /* = sig(i) * k*tanh(g) */            \
    cc = fmaf(fv, cc, pp);           /* state is k-scaled: cc = k*c */     \
    const float ec = fast_ex2(-cc);  /* = exp2(2*log2e*c) = e^{2c} */      \
    const float rc = fast_rcp(1.0f + ec);                                  \
    const float ov2 = ov + ov;                                             \
    hh = fmaf(-ov2, rc, ov);         /* ov*tanh(c) = ov - 2*ov*rc */       \
  }

__global__ __launch_bounds__(256) void lstm_kernel(
    const float* __restrict__ x, const float* __restrict__ w_ih,
    const float* __restrict__ w_hh, const float* __restrict__ b_ih,
    const float* __restrict__ b_hh, const float* __restrict__ w_fc,
    const float* __restrict__ b_fc, float* __restrict__ out, int B, int T) {
  const int tid = threadIdx.x;
  const int lg = tid & 15;              // lane within 16-lane group
  const int grp = tid >> 4;             // group within block (0..15)
  const int b = blockIdx.x * 16 + grp;  // batch element

  const int gA = lg;       // gate row: i (lg<8) or f (lg>=8)
  const int gB = lg + 16;  // gate row: g (lg<8) or o (lg>=8)
  const int j = lg & 7;    // owned h/c element
  const bool lo8 = (lg < 8);

  // Fold the exp2 argument scale m into weights & bias:
  //   sigmoid rows: m = -log2e;  tanh rows (gB, lg<8): m = -2*log2e.
  const float mA = -LOG2E;
  const float mB = lo8 ? (-2.0f * LOG2E) : (-LOG2E);
  v2f wsc[8];
#pragma unroll
  for (int r = 0; r < 8; ++r) {
    const int jr = (lg - r) & 7;
    wsc[r] = (v2f){w_hh[gA * 8 + jr] * mA, w_hh[gB * 8 + jr] * mB};
  }
  const v2f wih2 = (v2f){w_ih[gA] * mA, w_ih[gB] * mB};
  const v2f bias2 =
      (v2f){(b_ih[gA] + b_hh[gA]) * mA, (b_ih[gB] + b_hh[gB]) * mB};
  // sB affine: g-rows produce k*tanh(g) with k=-2log2e (keeps c k-scaled):
  //   k*tanh = (2k)*rcp(1+e) + (-k).  o-rows: plain sigmoid (A=1,B=0).
  const float AB = lo8 ? (-4.0f * LOG2E) : 1.0f;
  const float BB = lo8 ? (2.0f * LOG2E) : 0.0f;

  float hh = 0.0f;  // h_{lg&7} (duplicated in both 8-halves)
  float cc = 0.0f;  // k-scaled c_{lg&7}

  const float* xp = x + (size_t)b * T + lg;
  const int NBLK = T / 16;  // 128

  // Prologue: xg for block 0; prefetch block 1.
  v2f xgA[16], xgB[16];
  {
    const float x0 = xp[0];
#pragma unroll
    for (int s = 0; s < 16; ++s)
      xgA[s] = fma2(splat2(xbcast_s(x0, s)), wih2, bias2);
  }
  float xnxt = xp[16];  // block 1 data

  for (int blk = 0; blk < NBLK; blk += 2) {
    // Prefetch block blk+2 (clamped; tail builds are unused but harmless).
    const int o2 = (blk + 2 < NBLK ? blk + 2 : NBLK - 1) * 16;
    const float xpre = xp[o2];
    PROCESS_BLOCK(xgA, xgB, xnxt)  // process blk, build xg for blk+1
    const int o3 = (blk + 3 < NBLK ? blk + 3 : NBLK - 1) * 16;
    const float xpre2 = xp[o3];
    PROCESS_BLOCK(xgB, xgA, xpre)  // process blk+1, build xg for blk+2
    xnxt = xpre2;
  }

  // ---- final FC: out[b, q] = b_fc[q] + sum_k h_k * w_fc[q, k]
  __shared__ float sh[16 * 8];
  if (lo8) sh[grp * 8 + j] = hh;
  __syncthreads();
  if (lg < 4) {
    float acc = b_fc[lg];
#pragma unroll
    for (int k = 0; k < 8; ++k)
      acc = fmaf(sh[grp * 8 + k], w_fc[lg * 8 + k], acc);
    out[(size_t)b * 4 + lg] = acc;
  }
}

extern "C" void kernel_launch(void* const* d_in, const int* in_sizes, int n_in,
                              void* d_out, int out_size, void* d_ws,
                              size_t ws_size, hipStream_t stream) {
  const float* x = (const float*)d_in[0];
  const float* w_ih = (const float*)d_in[1];
  const float* w_hh = (const float*)d_in[2];
  const float* b_ih = (const float*)d_in[3];
  const float* b_hh = (const float*)d_in[4];
  const float* w_fc = (const float*)d_in[5];
  const float* b_fc = (const float*)d_in[6];
  float* out = (float*)d_out;

  const int T = 2048;
  const int B = in_sizes[0] / T;  // 4096

  dim3 grid(B / 16);  // 16 batches per 256-thread block
  dim3 block(256);
  hipLaunchKernelGGL(lstm_kernel, grid, block, 0, stream, x, w_ih, w_hh, b_ih,
                     b_hh, w_fc, b_fc, out, B, T);
}

// Round 4
// 276.103 us; speedup vs baseline: 1.0900x; 1.0032x over previous
//
#include <hip/hip_runtime.h>

// LSTM (H=8, I=1), B=4096, T=2048, then FC [8->4].
//
// Mapping: 16 lanes per batch element (wave64 = 4 batches; 1024 waves =
// 1 wave/SIMD on 256 CUs -> wall time == serial chain latency per step).
// Lane lg in [0,16): gate rows gA=lg (i|f), gB=lg+16 (g|o); owns c_j,h_j for
// j=lg&7, h duplicated in both 8-halves so DPP row_ror:r rotates mod 8.
//
// R4: the per-step ds_swizzle (xg build) was injecting DS latency into every
// step (s_waitcnt lgkmcnt(0) before the dependent pk_fma). x is
// group-uniform and contiguous -> replace all cross-lane x traffic with
// float4 global loads double-buffered 2 blocks ahead (vmcnt, off-chain).
// Also: ROR8+cndmask exchange -> bank-masked update_dpp merge (-1 hop).

typedef float v2f __attribute__((ext_vector_type(2)));

#define LOG2E 1.4426950408889634f

template <int CTRL>
__device__ __forceinline__ float dpp_mov(float v) {
  return __int_as_float(
      __builtin_amdgcn_update_dpp(0, __float_as_int(v), CTRL, 0xF, 0xF, true));
}
// Masked DPP merge: enabled banks get the rotated src, disabled keep old.
// bank_mask bit k = lanes [4k,4k+3] of each 16-lane row.
template <int CTRL, int BANK>
__device__ __forceinline__ float dpp_merge(float old_v, float src) {
  return __int_as_float(__builtin_amdgcn_update_dpp(
      __float_as_int(old_v), __float_as_int(src), CTRL, 0xF, BANK, false));
}
#define ROR(n) (0x120 + (n))  // row_ror:n within 16-lane rows

__device__ __forceinline__ float fast_ex2(float x) {
#if __has_builtin(__builtin_amdgcn_exp2f)
  return __builtin_amdgcn_exp2f(x);
#else
  return __exp2f(x);
#endif
}
__device__ __forceinline__ float fast_rcp(float x) {
#if __has_builtin(__builtin_amdgcn_rcpf)
  return __builtin_amdgcn_rcpf(x);
#else
  return 1.0f / x;
#endif
}
__device__ __forceinline__ v2f fma2(v2f a, v2f b, v2f c) {
  return __builtin_elementwise_fma(a, b, c);
}
__device__ __forceinline__ v2f splat2(float v) { return (v2f){v, v}; }

// Build the 16 precomputed gate inputs for one block from 4 float4 regs.
#define BUILD_XG(XG, Q0, Q1, Q2, Q3)                  \
  XG[0] = fma2(splat2((Q0).x), wih2, bias2);          \
  XG[1] = fma2(splat2((Q0).y), wih2, bias2);          \
  XG[2] = fma2(splat2((Q0).z), wih2, bias2);          \
  XG[3] = fma2(splat2((Q0).w), wih2, bias2);          \
  XG[4] = fma2(splat2((Q1).x), wih2, bias2);          \
  XG[5] = fma2(splat2((Q1).y), wih2, bias2);          \
  XG[6] = fma2(splat2((Q1).z), wih2, bias2);          \
  XG[7] = fma2(splat2((Q1).w), wih2, bias2);          \
  XG[8] = fma2(splat2((Q2).x), wih2, bias2);          \
  XG[9] = fma2(splat2((Q2).y), wih2, bias2);          \
  XG[10] = fma2(splat2((Q2).z), wih2, bias2);         \
  XG[11] = fma2(splat2((Q2).w), wih2, bias2);         \
  XG[12] = fma2(splat2((Q3).x), wih2, bias2);         \
  XG[13] = fma2(splat2((Q3).y), wih2, bias2);         \
  XG[14] = fma2(splat2((Q3).z), wih2, bias2);         \
  XG[15] = fma2(splat2((Q3).w), wih2, bias2);

// 16 serial LSTM steps consuming XG[0..15]. No DS ops, no loads.
#define STEPS16(XG)                                                        \
  _Pragma("unroll") for (int s = 0; s < 16; ++s) {                         \
    const v2f xgs = XG[s];                                                 \
    const float r1 = dpp_mov<ROR(1)>(hh);                                  \
    const float r2 = dpp_mov<ROR(2)>(hh);                                  \
    const float r3 = dpp_mov<ROR(3)>(hh);                                  \
    const float r4 = dpp_mov<ROR(4)>(hh);                                  \
    const float r5 = dpp_mov<ROR(5)>(hh);                                  \
    const float r6 = dpp_mov<ROR(6)>(hh);                                  \
    const float r7 = dpp_mov<ROR(7)>(hh);                                  \
    v2f t0 = fma2(splat2(hh), wsc[0], xgs);                                \
    v2f t1 = splat2(r1) * wsc[1];                                          \
    v2f t2 = splat2(r4) * wsc[4];                                          \
    v2f t3 = splat2(r5) * wsc[5];                                          \
    t0 = fma2(splat2(r2), wsc[2], t0);                                     \
    t1 = fma2(splat2(r3), wsc[3], t1);                                     \
    t2 = fma2(splat2(r6), wsc[6], t2);                                     \
    t3 = fma2(splat2(r7), wsc[7], t3);                                     \
    const v2f gg = (t0 + t1) + (t2 + t3);                                  \
    const float e0 = fast_ex2(gg.x); /* gate scale folded into weights */  \
    const float e1 = fast_ex2(gg.y);                                       \
    const float sA = fast_rcp(1.0f + e0);               /* sig(i|f) */     \
    const float sB = fmaf(fast_rcp(1.0f + e1), AB, BB); /* ktanh|sig(o) */ \
    const float p1 = sA * sB;                                              \
    /* half-exchange via bank-masked DPP (lanes keep own value where */    \
    /* masked): fv/ov update lanes 0-7, pp updates lanes 8-15.      */     \
    const float fv = dpp_merge<ROR(8), 0x3>(sA, sA);                       \
    const float ov = dpp_merge<ROR(8), 0x3>(sB, sB);                       \
    const float pp = dpp_merge<ROR(8), 0xC>(p1, p1);                       \
    cc = fmaf(fv, cc, pp);          /* cc = k*c, k = -2*log2e */           \
    const float ec = fast_ex2(-cc); /* e^{2c} */                           \
    const float rc = fast_rcp(1.0f + ec);                                  \
    const float ov2 = ov + ov;                                             \
    hh = fmaf(-ov2, rc, ov); /* ov*tanh(c) = ov - 2*ov*rc */               \
  }

__global__ __launch_bounds__(256) void lstm_kernel(
    const float* __restrict__ x, const float* __restrict__ w_ih,
    const float* __restrict__ w_hh, const float* __restrict__ b_ih,
    const float* __restrict__ b_hh, const float* __restrict__ w_fc,
    const float* __restrict__ b_fc, float* __restrict__ out, int B, int T) {
  const int tid = threadIdx.x;
  const int lg = tid & 15;              // lane within 16-lane group
  const int grp = tid >> 4;             // group within block (0..15)
  const int b = blockIdx.x * 16 + grp;  // batch element

  const int gA = lg;       // gate row: i (lg<8) or f (lg>=8)
  const int gB = lg + 16;  // gate row: g (lg<8) or o (lg>=8)
  const int j = lg & 7;    // owned h/c element
  const bool lo8 = (lg < 8);

  // exp2 argument scale folded into weights & bias:
  //   sigmoid rows: m=-log2e; tanh rows (gB, lg<8): m=-2log2e.
  const float mA = -LOG2E;
  const float mB = lo8 ? (-2.0f * LOG2E) : (-LOG2E);
  v2f wsc[8];
#pragma unroll
  for (int r = 0; r < 8; ++r) {
    const int jr = (lg - r) & 7;
    wsc[r] = (v2f){w_hh[gA * 8 + jr] * mA, w_hh[gB * 8 + jr] * mB};
  }
  const v2f wih2 = (v2f){w_ih[gA] * mA, w_ih[gB] * mB};
  const v2f bias2 =
      (v2f){(b_ih[gA] + b_hh[gA]) * mA, (b_ih[gB] + b_hh[gB]) * mB};
  // g-rows produce k*tanh(g), k=-2log2e (keeps c k-scaled): A=2k, B=-k.
  const float AB = lo8 ? (-4.0f * LOG2E) : 1.0f;
  const float BB = lo8 ? (2.0f * LOG2E) : 0.0f;

  float hh = 0.0f;  // h_{lg&7} (duplicated in both 8-halves)
  float cc = 0.0f;  // k-scaled c_{lg&7}

  const float4* xq = (const float4*)(x + (size_t)b * T);  // 4 quads per block
  const int NBLK = T / 16;  // 128

  v2f xg[16];
  // Double-buffered x quads: a = even block, b = odd block.
  float4 a0 = xq[0], a1 = xq[1], a2 = xq[2], a3 = xq[3];
  float4 c0 = xq[4], c1 = xq[5], c2 = xq[6], c3 = xq[7];

  for (int blk = 0; blk < NBLK; blk += 2) {
    {
      BUILD_XG(xg, a0, a1, a2, a3)  // xg for blk (uses old a regs)
      const int nb = (blk + 2 < NBLK ? blk + 2 : NBLK - 1) * 4;
      a0 = xq[nb + 0]; a1 = xq[nb + 1]; a2 = xq[nb + 2]; a3 = xq[nb + 3];
      STEPS16(xg)
    }
    {
      BUILD_XG(xg, c0, c1, c2, c3)  // xg for blk+1
      const int nb = (blk + 3 < NBLK ? blk + 3 : NBLK - 1) * 4;
      c0 = xq[nb + 0]; c1 = xq[nb + 1]; c2 = xq[nb + 2]; c3 = xq[nb + 3];
      STEPS16(xg)
    }
  }

  // ---- final FC: out[b, q] = b_fc[q] + sum_k h_k * w_fc[q, k]
  __shared__ float sh[16 * 8];
  if (lo8) sh[grp * 8 + j] = hh;
  __syncthreads();
  if (lg < 4) {
    float acc = b_fc[lg];
#pragma unroll
    for (int k = 0; k < 8; ++k)
      acc = fmaf(sh[grp * 8 + k], w_fc[lg * 8 + k], acc);
    out[(size_t)b * 4 + lg] = acc;
  }
}

extern "C" void kernel_launch(void* const* d_in, const int* in_sizes, int n_in,
                              void* d_out, int out_size, void* d_ws,
                              size_t ws_size, hipStream_t stream) {
  const float* x = (const float*)d_in[0];
  const float* w_ih = (const float*)d_in[1];
  const float* w_hh = (const float*)d_in[2];
  const float* b_ih = (const float*)d_in[3];
  const float* b_hh = (const float*)d_in[4];
  const float* w_fc = (const float*)d_in[5];
  const float* b_fc = (const float*)d_in[6];
  float* out = (float*)d_out;

  const int T = 2048;
  const int B = in_sizes[0] / T;  // 4096

  dim3 grid(B / 16);  // 16 batches per 256-thread block
  dim3 block(256);
  hipLaunchKernelGGL(lstm_kernel, grid, block, 0, stream, x, w_ih, w_hh, b_ih,
                     b_hh, w_fc, b_fc, out, B, T);
}

// Round 5
// 270.991 us; speedup vs baseline: 1.1106x; 1.0189x over previous
//
#include <hip/hip_runtime.h>

// LSTM (H=8, I=1), B=4096, T=2048, then FC [8->4].
//
// Mapping: 16 lanes per batch element (wave64 = 4 batches; 1024 waves =
// 1 wave/SIMD on 256 CUs). Lane lg in [0,16): gate rows gA=lg (i|f), gB=lg+16
// (g|o); owns c_j,h_j for j=lg&7, h duplicated in both 8-halves so DPP
// row_ror:r rotates mod 8.
//
// R5 (issue-bound per R4 counters; trans ops ~16cy each dominate):
//  - ONE v_rcp for both gate sigmoids: r = rcp((1+e0)(1+e1)),
//    1/(1+e0) = (1+e1)*r.  Trans 6 -> 5 per step.
//  - 2-accumulator matvec (8 pk_fma + 1 pk_add, was +3 adds).
//  - xg builds distributed one-per-step (stall filler), from float4 regs
//    double-buffered two blocks ahead. No DS ops anywhere in the T-loop.

typedef float v2f __attribute__((ext_vector_type(2)));

#define LOG2E 1.4426950408889634f

template <int CTRL>
__device__ __forceinline__ float dpp_mov(float v) {
  return __int_as_float(
      __builtin_amdgcn_update_dpp(0, __float_as_int(v), CTRL, 0xF, 0xF, true));
}
// Masked DPP merge: enabled banks (4-lane groups) take rotated src, others
// keep old.
template <int CTRL, int BANK>
__device__ __forceinline__ float dpp_merge(float old_v, float src) {
  return __int_as_float(__builtin_amdgcn_update_dpp(
      __float_as_int(old_v), __float_as_int(src), CTRL, 0xF, BANK, false));
}
#define ROR(n) (0x120 + (n))  // row_ror:n within 16-lane rows

__device__ __forceinline__ float fast_ex2(float x) {
#if __has_builtin(__builtin_amdgcn_exp2f)
  return __builtin_amdgcn_exp2f(x);
#else
  return __exp2f(x);
#endif
}
__device__ __forceinline__ float fast_rcp(float x) {
#if __has_builtin(__builtin_amdgcn_rcpf)
  return __builtin_amdgcn_rcpf(x);
#else
  return 1.0f / x;
#endif
}
__device__ __forceinline__ v2f fma2(v2f a, v2f b, v2f c) {
  return __builtin_elementwise_fma(a, b, c);
}
__device__ __forceinline__ v2f splat2(float v) { return (v2f){v, v}; }

__device__ __forceinline__ float quad_c(const float4& q, int c) {
  switch (c) {
    case 0: return q.x;
    case 1: return q.y;
    case 2: return q.z;
    default: return q.w;
  }
}

// 16 serial LSTM steps consuming XG[0..15]; builds XGN[s] (next block's gate
// inputs) from quad regs Q[0..3] one per step — pure register ILP filler.
#define STEPS16(XG, XGN, Q)                                                 \
  _Pragma("unroll") for (int s = 0; s < 16; ++s) {                          \
    XGN[s] = fma2(splat2(quad_c(Q[s >> 2], s & 3)), wih2, bias2);           \
    const v2f xgs = XG[s];                                                  \
    const float r1 = dpp_mov<ROR(1)>(hh);                                   \
    const float r2 = dpp_mov<ROR(2)>(hh);                                   \
    const float r3 = dpp_mov<ROR(3)>(hh);                                   \
    const float r4 = dpp_mov<ROR(4)>(hh);                                   \
    const float r5 = dpp_mov<ROR(5)>(hh);                                   \
    const float r6 = dpp_mov<ROR(6)>(hh);                                   \
    const float r7 = dpp_mov<ROR(7)>(hh);                                   \
    v2f t0 = fma2(splat2(hh), wsc[0], xgs);                                 \
    v2f t1 = splat2(r1) * wsc[1];                                           \
    t0 = fma2(splat2(r2), wsc[2], t0);                                      \
    t1 = fma2(splat2(r3), wsc[3], t1);                                      \
    t0 = fma2(splat2(r4), wsc[4], t0);                                      \
    t1 = fma2(splat2(r5), wsc[5], t1);                                      \
    t0 = fma2(splat2(r6), wsc[6], t0);                                      \
    t1 = fma2(splat2(r7), wsc[7], t1);                                      \
    const v2f gg = t0 + t1;                                                 \
    const float e0 = fast_ex2(gg.x); /* gate scale folded in weights */     \
    const float e1 = fast_ex2(gg.y);                                        \
    const v2f dd = (v2f){e0, e1} + (v2f){1.0f, 1.0f};                       \
    const float rD = fast_rcp(dd.x * dd.y); /* ONE rcp for both gates */    \
    const float sA = dd.y * rD;                     /* sig(i|f) */          \
    const float sB = fmaf(dd.x * rD, AB, BB);       /* ktanh(g)|sig(o) */   \
    const float p1 = sA * sB;                                               \
    /* half-exchange via bank-masked DPP */                                 \
    const float fv = dpp_merge<ROR(8), 0x3>(sA, sA);                        \
    const float ov = dpp_merge<ROR(8), 0x3>(sB, sB);                        \
    const float pp = dpp_merge<ROR(8), 0xC>(p1, p1);                        \
    cc = fmaf(fv, cc, pp);          /* cc = k*c, k = -2*log2e */            \
    const float ec = fast_ex2(-cc); /* e^{2c} */                            \
    const float rc = fast_rcp(1.0f + ec);                                   \
    const float ov2 = ov + ov;                                              \
    hh = fmaf(-ov2, rc, ov); /* ov*tanh(c) = ov - 2*ov*rc */                \
  }

__global__ __launch_bounds__(256) void lstm_kernel(
    const float* __restrict__ x, const float* __restrict__ w_ih,
    const float* __restrict__ w_hh, const float* __restrict__ b_ih,
    const float* __restrict__ b_hh, const float* __restrict__ w_fc,
    const float* __restrict__ b_fc, float* __restrict__ out, int B, int T) {
  const int tid = threadIdx.x;
  const int lg = tid & 15;              // lane within 16-lane group
  const int grp = tid >> 4;             // group within block (0..15)
  const int b = blockIdx.x * 16 + grp;  // batch element

  const int gA = lg;       // gate row: i (lg<8) or f (lg>=8)
  const int gB = lg + 16;  // gate row: g (lg<8) or o (lg>=8)
  const int j = lg & 7;    // owned h/c element
  const bool lo8 = (lg < 8);

  // exp2 argument scale folded into weights & bias:
  //   sigmoid rows: m=-log2e; tanh rows (gB, lg<8): m=-2log2e.
  const float mA = -LOG2E;
  const float mB = lo8 ? (-2.0f * LOG2E) : (-LOG2E);
  v2f wsc[8];
#pragma unroll
  for (int r = 0; r < 8; ++r) {
    const int jr = (lg - r) & 7;
    wsc[r] = (v2f){w_hh[gA * 8 + jr] * mA, w_hh[gB * 8 + jr] * mB};
  }
  const v2f wih2 = (v2f){w_ih[gA] * mA, w_ih[gB] * mB};
  const v2f bias2 =
      (v2f){(b_ih[gA] + b_hh[gA]) * mA, (b_ih[gB] + b_hh[gB]) * mB};
  // g-rows produce k*tanh(g), k=-2log2e (keeps c k-scaled): A=2k, B=-k.
  const float AB = lo8 ? (-4.0f * LOG2E) : 1.0f;
  const float BB = lo8 ? (2.0f * LOG2E) : 0.0f;

  float hh = 0.0f;  // h_{lg&7} (duplicated in both 8-halves)
  float cc = 0.0f;  // k-scaled c_{lg&7}

  const float4* xq = (const float4*)(x + (size_t)b * T);
  const int NBLK = T / 16;  // 128

  v2f xgA[16], xgB[16];
  float4 qa[4], qb[4];
#pragma unroll
  for (int i = 0; i < 4; ++i) qa[i] = xq[i];      // block 0
#pragma unroll
  for (int i = 0; i < 4; ++i) qb[i] = xq[4 + i];  // block 1
  // Prologue: xg for block 0.
#pragma unroll
  for (int s = 0; s < 16; ++s)
    xgA[s] = fma2(splat2(quad_c(qa[s >> 2], s & 3)), wih2, bias2);

  for (int blk = 0; blk < NBLK; blk += 2) {
    {
      const int nb = (blk + 2 < NBLK ? blk + 2 : NBLK - 1) * 4;
#pragma unroll
      for (int i = 0; i < 4; ++i) qa[i] = xq[nb + i];  // prefetch blk+2
      STEPS16(xgA, xgB, qb)  // run blk; build xg for blk+1 from qb
    }
    {
      const int nb = (blk + 3 < NBLK ? blk + 3 : NBLK - 1) * 4;
#pragma unroll
      for (int i = 0; i < 4; ++i) qb[i] = xq[nb + i];  // prefetch blk+3
      STEPS16(xgB, xgA, qa)  // run blk+1; build xg for blk+2 from qa
    }
  }

  // ---- final FC: out[b, q] = b_fc[q] + sum_k h_k * w_fc[q, k]
  __shared__ float sh[16 * 8];
  if (lo8) sh[grp * 8 + j] = hh;
  __syncthreads();
  if (lg < 4) {
    float acc = b_fc[lg];
#pragma unroll
    for (int k = 0; k < 8; ++k)
      acc = fmaf(sh[grp * 8 + k], w_fc[lg * 8 + k], acc);
    out[(size_t)b * 4 + lg] = acc;
  }
}

extern "C" void kernel_launch(void* const* d_in, const int* in_sizes, int n_in,
                              void* d_out, int out_size, void* d_ws,
                              size_t ws_size, hipStream_t stream) {
  const float* x = (const float*)d_in[0];
  const float* w_ih = (const float*)d_in[1];
  const float* w_hh = (const float*)d_in[2];
  const float* b_ih = (const float*)d_in[3];
  const float* b_hh = (const float*)d_in[4];
  const float* w_fc = (const float*)d_in[5];
  const float* b_fc = (const float*)d_in[6];
  float* out = (float*)d_out;

  const int T = 2048;
  const int B = in_sizes[0] / T;  // 4096

  dim3 grid(B / 16);  // 16 batches per 256-thread block
  dim3 block(256);
  hipLaunchKernelGGL(lstm_kernel, grid, block, 0, stream, x, w_ih, w_hh, b_ih,
                     b_hh, w_fc, b_fc, out, B, T);
}